// Round 8
// baseline (5563.252 us; speedup 1.0000x reference)
//
#include <hip/hip_runtime.h>
#include <stdint.h>

// ---------------- constants ----------------
#define HID   1024          // H
#define B3H   3072          // 3H
#define BSZ   256           // batch
#define TLEN  128           // seq len
#define VOC   512
#define EMB   512
#define SLAB  ((size_t)BSZ * B3H)    // one [256,3072] f32 slab (elements)

typedef unsigned short u16;
typedef short bf16x8 __attribute__((ext_vector_type(8)));
typedef float f32x4  __attribute__((ext_vector_type(4)));

__device__ __forceinline__ float bf2f(u16 u) {
    union { float f; uint32_t i; } c; c.i = ((uint32_t)u) << 16; return c.f;
}
__device__ __forceinline__ u16 f2bf(float f) {
    union { float f; uint32_t i; } c; c.f = f;
    uint32_t u = c.i;
    return (u16)((u + 0x7FFFu + ((u >> 16) & 1u)) >> 16);   // RNE
}
__device__ __forceinline__ float sigm(float x)  { return 1.f / (1.f + __expf(-x)); }
__device__ __forceinline__ float tanhf_(float x) {
    float e = __expf(-2.f * fabsf(x));
    float r = (1.f - e) / (1.f + e);
    return x < 0.f ? -r : r;
}

// async global->LDS, 16B per lane (wave-uniform LDS base + lane*16)
__device__ __forceinline__ void gll16(const u16* g, u16* l) {
    __builtin_amdgcn_global_load_lds(
        (__attribute__((address_space(1))) void*)(u16*)g,
        (__attribute__((address_space(3))) void*)l, 16, 0, 0);
}

// stage one 128x32 bf16 tile (row-major src, stride ld) into linear LDS [128][32]
__device__ __forceinline__ void stage_tile(const u16* __restrict__ src, int ld,
                                           u16* __restrict__ lds, int wid, int lane) {
#pragma unroll
    for (int i = 0; i < 2; i++) {
        int row16 = wid * 2 + i;                       // 0..7 (16-row groups)
        const u16* g = src + (size_t)(row16 * 16 + (lane >> 2)) * ld + (lane & 3) * 8;
        u16* l = lds + row16 * 16 * 32;                // wave-uniform base
        gll16(g, l);
    }
}
// stage one 64x32 tile: 1 instr per wave (wave w covers rows w*16..w*16+15)
__device__ __forceinline__ void stage_tile64(const u16* __restrict__ src, int ld,
                                             u16* __restrict__ lds, int wid, int lane) {
    const u16* g = src + (size_t)(wid * 16 + (lane >> 2)) * ld + (lane & 3) * 8;
    gll16(g, lds + wid * 16 * 32);
}

// 128x128 x KTOT staged GEMM core: 4 waves, each 64x64 (acc[4][4])
template<int KTOT>
__device__ __forceinline__ void gemm_tiles(const u16* __restrict__ A, const u16* __restrict__ W,
                                           f32x4 acc[4][4], int wid, int lane) {
    __shared__ u16 As[2][128 * 32], Ws[2][128 * 32];
    const int r = lane & 15, g8 = (lane >> 4) * 8;
    const int mq = wid & 1, nq = wid >> 1;
    int buf = 0;
    stage_tile(A, KTOT, As[0], wid, lane);
    stage_tile(W, KTOT, Ws[0], wid, lane);
    __syncthreads();
    for (int k0 = 0; k0 < KTOT; k0 += 32) {
        if (k0 + 32 < KTOT) {
            stage_tile(A + k0 + 32, KTOT, As[buf ^ 1], wid, lane);
            stage_tile(W + k0 + 32, KTOT, Ws[buf ^ 1], wid, lane);
        }
        bf16x8 a[4], b[4];
#pragma unroll
        for (int i = 0; i < 4; i++) a[i] = *(const bf16x8*)(As[buf] + (mq * 64 + i * 16 + r) * 32 + g8);
#pragma unroll
        for (int i = 0; i < 4; i++) b[i] = *(const bf16x8*)(Ws[buf] + (nq * 64 + i * 16 + r) * 32 + g8);
#pragma unroll
        for (int mi = 0; mi < 4; mi++)
#pragma unroll
            for (int ni = 0; ni < 4; ni++)
                acc[mi][ni] = __builtin_amdgcn_mfma_f32_16x16x32_bf16(a[mi], b[ni], acc[mi][ni], 0, 0, 0);
        __syncthreads();
        buf ^= 1;
    }
}

// 64(M) x 128(N) x KTOT staged core: 4 waves, each 32x64 (acc[2][4]); LDS 24 KB
template<int KTOT>
__device__ __forceinline__ void gemm_tiles64(const u16* __restrict__ A, const u16* __restrict__ W,
                                             f32x4 acc[2][4], int wid, int lane) {
    __shared__ u16 As[2][64 * 32], Ws[2][128 * 32];
    const int r = lane & 15, g8 = (lane >> 4) * 8;
    const int mq = wid & 1, nq = wid >> 1;
    int buf = 0;
    stage_tile64(A, KTOT, As[0], wid, lane);
    stage_tile(W, KTOT, Ws[0], wid, lane);
    __syncthreads();
    for (int k0 = 0; k0 < KTOT; k0 += 32) {
        if (k0 + 32 < KTOT) {
            stage_tile64(A + k0 + 32, KTOT, As[buf ^ 1], wid, lane);
            stage_tile(W + k0 + 32, KTOT, Ws[buf ^ 1], wid, lane);
        }
        bf16x8 a[2], b[4];
#pragma unroll
        for (int i = 0; i < 2; i++) a[i] = *(const bf16x8*)(As[buf] + (mq * 32 + i * 16 + r) * 32 + g8);
#pragma unroll
        for (int i = 0; i < 4; i++) b[i] = *(const bf16x8*)(Ws[buf] + (nq * 64 + i * 16 + r) * 32 + g8);
#pragma unroll
        for (int mi = 0; mi < 2; mi++)
#pragma unroll
            for (int ni = 0; ni < 4; ni++)
                acc[mi][ni] = __builtin_amdgcn_mfma_f32_16x16x32_bf16(a[mi], b[ni], acc[mi][ni], 0, 0, 0);
        __syncthreads();
        buf ^= 1;
    }
}

// ---------------- tiny utility kernels ----------------
__global__ void k_convert(const float* __restrict__ in, u16* __restrict__ out, int n) {
    int i = (blockIdx.x * 256 + threadIdx.x) * 4;
    if (i >= n) return;
    float4 f = *(const float4*)(in + i);
    uint32_t lo = (uint32_t)f2bf(f.x) | ((uint32_t)f2bf(f.y) << 16);
    uint32_t hi = (uint32_t)f2bf(f.z) | ((uint32_t)f2bf(f.w) << 16);
    uint2 p; p.x = lo; p.y = hi;
    *(uint2*)(out + i) = p;
}

// ---------------- staged proj: X_all = emb[tok] @ projW^T + projb (gathered A) ----------------
__global__ void __launch_bounds__(256) k_proj_s(const u16* __restrict__ emb_bf, const u16* __restrict__ projW_bf,
                        const float* __restrict__ projb, const int* __restrict__ target,
                        u16* __restrict__ X_all) {
    int nt = blockIdx.x, mt = blockIdx.y;
    int wid = threadIdx.x >> 6, lane = threadIdx.x & 63;
    __shared__ u16 As[2][128 * 32], Ws[2][128 * 32];
    // per-lane gathered A row pointers (2 gll16 per wave -> rows wid*32..wid*32+31)
    const u16* arow[2];
#pragma unroll
    for (int i = 0; i < 2; i++) {
        int lr = (wid * 2 + i) * 16 + (lane >> 2);     // 0..127
        int gr = mt * 128 + lr;
        int t = gr >> 8, b = gr & 255;
        int tok = (t == 0) ? 0 : target[b * TLEN + t - 1];
        arow[i] = emb_bf + (size_t)tok * EMB + (lane & 3) * 8;
    }
    const u16* W = projW_bf + (size_t)(nt * 128) * EMB;
    const int r = lane & 15, g8 = (lane >> 4) * 8;
    const int mq = wid & 1, nq = wid >> 1;
    f32x4 acc[4][4] = {};
    int buf = 0;
#pragma unroll
    for (int i = 0; i < 2; i++) gll16(arow[i], As[0] + (wid * 2 + i) * 512);
    stage_tile(W, EMB, Ws[0], wid, lane);
    __syncthreads();
    for (int k0 = 0; k0 < EMB; k0 += 32) {
        if (k0 + 32 < EMB) {
#pragma unroll
            for (int i = 0; i < 2; i++) gll16(arow[i] + k0 + 32, As[buf ^ 1] + (wid * 2 + i) * 512);
            stage_tile(W + k0 + 32, EMB, Ws[buf ^ 1], wid, lane);
        }
        bf16x8 a[4], b[4];
#pragma unroll
        for (int i = 0; i < 4; i++) a[i] = *(const bf16x8*)(As[buf] + (mq * 64 + i * 16 + r) * 32 + g8);
#pragma unroll
        for (int i = 0; i < 4; i++) b[i] = *(const bf16x8*)(Ws[buf] + (nq * 64 + i * 16 + r) * 32 + g8);
#pragma unroll
        for (int mi = 0; mi < 4; mi++)
#pragma unroll
            for (int ni = 0; ni < 4; ni++)
                acc[mi][ni] = __builtin_amdgcn_mfma_f32_16x16x32_bf16(a[mi], b[ni], acc[mi][ni], 0, 0, 0);
        __syncthreads();
        buf ^= 1;
    }
    int c = lane & 15, r0 = (lane >> 4) * 4;
#pragma unroll
    for (int mi = 0; mi < 4; mi++)
#pragma unroll
        for (int e = 0; e < 4; e++) {
            size_t row = (size_t)(mt * 128 + mq * 64 + mi * 16 + r0 + e);
#pragma unroll
            for (int ni = 0; ni < 4; ni++) {
                int col = nt * 128 + nq * 64 + ni * 16 + c;
                X_all[row * HID + col] = f2bf(acc[mi][ni][e] + projb[col]);
            }
        }
}

// ============== wavefront GEMM (staged 64x128): 6 groups x 4 Mtiles x 24 Ntiles ==============
// bid = g*96 + mt*24 + nt  (W-panel sharers mt=0..3 differ by 24 == 0 mod 8 -> same XCD)
__global__ void __launch_bounds__(256) k_gstep(int wv,
    const u16* __restrict__ X_all, const u16* __restrict__ h_bf,
    const u16* __restrict__ Wih, const u16* __restrict__ Whh,
    float* __restrict__ giP, float* __restrict__ ghP) {
    int bid = blockIdx.x;
    int g = bid / 96, rem = bid % 96, mt = rem / 24, nt = rem % 24;
    int cell = g % 3; bool isgh = (g >= 3);
    int t = wv - cell;
    if (t < 0 || t >= TLEN) return;
    int rd = (wv + 1) & 1;
    const u16* A;
    if (isgh)            A = h_bf + (size_t)(rd * 3 + cell)     * BSZ * HID;
    else if (cell == 0)  A = X_all + (size_t)t * BSZ * HID;
    else                 A = h_bf + (size_t)(rd * 3 + cell - 1) * BSZ * HID;
    A += (size_t)(mt * 64) * HID;
    const u16* W = (isgh ? Whh : Wih) + (size_t)cell * B3H * HID + (size_t)(nt * 128) * HID;
    float*     C = (isgh ? ghP : giP) + (size_t)cell * SLAB + (size_t)(mt * 64) * B3H + nt * 128;

    int wid = threadIdx.x >> 6, lane = threadIdx.x & 63;
    f32x4 acc[2][4] = {};
    gemm_tiles64<HID>(A, W, acc, wid, lane);
    int mq = wid & 1, nq = wid >> 1;
    int c = lane & 15, r0 = (lane >> 4) * 4;
#pragma unroll
    for (int mi = 0; mi < 2; mi++)
#pragma unroll
        for (int e = 0; e < 4; e++) {
            float* Cw = C + (size_t)(mq * 32 + mi * 16 + r0 + e) * B3H;
#pragma unroll
            for (int ni = 0; ni < 4; ni++)
                Cw[nq * 64 + ni * 16 + c] = acc[mi][ni][e];
        }
}

// ============== generic staged GEMM for the tail ==============
// EPI: 1 = bias+relu -> bf16 ; 2 = bias -> f32
template<int KTOT, int EPI>
__global__ void __launch_bounds__(256) k_gemm_s(const u16* __restrict__ A, const u16* __restrict__ W,
                                                const float* __restrict__ bias, void* __restrict__ Cout, int ldc) {
    int nt = blockIdx.x, mt = blockIdx.y;
    int wid = threadIdx.x >> 6, lane = threadIdx.x & 63;
    f32x4 acc[4][4] = {};
    gemm_tiles<KTOT>(A + (size_t)(mt * 128) * KTOT, W + (size_t)(nt * 128) * KTOT, acc, wid, lane);
    int mq = wid & 1, nq = wid >> 1;
    int c = lane & 15, r0 = (lane >> 4) * 4;
#pragma unroll
    for (int mi = 0; mi < 4; mi++)
#pragma unroll
        for (int e = 0; e < 4; e++) {
            size_t row = (size_t)(mt * 128 + mq * 64 + mi * 16 + r0 + e);
#pragma unroll
            for (int ni = 0; ni < 4; ni++) {
                int col = nt * 128 + nq * 64 + ni * 16 + c;
                float x = acc[mi][ni][e] + bias[col];
                if (EPI == 1) ((u16*)Cout)[row * ldc + col] = f2bf(fmaxf(x, 0.f));
                else          ((float*)Cout)[row * ldc + col] = x;
            }
        }
}

// ============== wavefront ew: 3 cells, 1 wave per batch row ==============
__global__ void __launch_bounds__(256) k_wew(int wv,
    const float* __restrict__ giP, const float* __restrict__ ghP,
    const float* __restrict__ bih_all, const float* __restrict__ bhh_all,
    float* __restrict__ h_f32, u16* __restrict__ h_bf, u16* __restrict__ X_all,
    const float* __restrict__ ln_s_all, const float* __restrict__ ln_b_all) {
    int cell = blockIdx.y;
    int t = wv - cell;
    if (t < 0 || t >= TLEN) return;
    int wid = threadIdx.x >> 6, lane = threadIdx.x & 63;
    int b = blockIdx.x * 4 + wid;
    int rd = (wv + 1) & 1, wr = wv & 1;

    const float* gi  = giP + (size_t)cell * SLAB + (size_t)b * B3H;
    const float* gh  = ghP + (size_t)cell * SLAB + (size_t)b * B3H;
    const float* bih = bih_all + cell * B3H;
    const float* bhh = bhh_all + cell * B3H;
    const float* lns = ln_s_all + cell * HID;
    const float* lnb = ln_b_all + cell * HID;
    const float* hprev = h_f32 + ((size_t)(rd * 3 + cell) * BSZ + b) * HID;
    float*       hout  = h_f32 + ((size_t)(wr * 3 + cell) * BSZ + b) * HID;
    u16*         hbout = h_bf  + ((size_t)(wr * 3 + cell) * BSZ + b) * HID;
    const float* xsrcf = (cell > 0) ? h_f32 + ((size_t)(rd * 3 + cell - 1) * BSZ + b) * HID : nullptr;
    const u16*   xsrcb = X_all + ((size_t)t * BSZ + b) * HID;

    float val[16], s = 0.f, s2 = 0.f;
#pragma unroll
    for (int e = 0; e < 4; e++) {
        int j = e * 256 + lane * 4;
        float gg[3][4], hh[3][4];
#pragma unroll
        for (int g = 0; g < 3; g++) {
            int o = g * HID + j;
            f32x4 a = __builtin_nontemporal_load((const f32x4*)(gi + o));
            float4 ab = *(const float4*)(bih + o);
            gg[g][0] = a[0] + ab.x; gg[g][1] = a[1] + ab.y; gg[g][2] = a[2] + ab.z; gg[g][3] = a[3] + ab.w;
            f32x4 h4 = __builtin_nontemporal_load((const f32x4*)(gh + o));
            float4 hb = *(const float4*)(bhh + o);
            hh[g][0] = h4[0] + hb.x; hh[g][1] = h4[1] + hb.y; hh[g][2] = h4[2] + hb.z; hh[g][3] = h4[3] + hb.w;
        }
        float4 hp = *(const float4*)(hprev + j);
        float hpv[4] = {hp.x, hp.y, hp.z, hp.w};
        float xv[4];
        if (cell == 0) {
            ushort4 u = *(const ushort4*)(xsrcb + j);
            xv[0] = bf2f(u.x); xv[1] = bf2f(u.y); xv[2] = bf2f(u.z); xv[3] = bf2f(u.w);
        } else {
            float4 x4 = *(const float4*)(xsrcf + j);
            xv[0] = x4.x; xv[1] = x4.y; xv[2] = x4.z; xv[3] = x4.w;
        }
#pragma unroll
        for (int q = 0; q < 4; q++) {
            float r = sigm(gg[0][q] + hh[0][q]);
            float z = sigm(gg[1][q] + hh[1][q]);
            float n = tanhf_(gg[2][q] + r * hh[2][q]);
            float v = (1.f - z) * n + z * hpv[q] + xv[q];
            val[e * 4 + q] = v; s += v; s2 += v * v;
        }
    }
#pragma unroll
    for (int o = 32; o > 0; o >>= 1) { s += __shfl_xor(s, o); s2 += __shfl_xor(s2, o); }
    float mu = s * (1.f / HID);
    float inv = rsqrtf(s2 * (1.f / HID) - mu * mu + 1e-5f);
#pragma unroll
    for (int e = 0; e < 4; e++) {
        int j = e * 256 + lane * 4;
        float4 sc = *(const float4*)(lns + j);
        float4 bi = *(const float4*)(lnb + j);
        float o0 = (val[e * 4 + 0] - mu) * inv * sc.x + bi.x;
        float o1 = (val[e * 4 + 1] - mu) * inv * sc.y + bi.y;
        float o2 = (val[e * 4 + 2] - mu) * inv * sc.z + bi.z;
        float o3 = (val[e * 4 + 3] - mu) * inv * sc.w + bi.w;
        float4 of; of.x = o0; of.y = o1; of.z = o2; of.w = o3;
        *(float4*)(hout + j) = of;
        u16 b0 = f2bf(o0), b1 = f2bf(o1), b2 = f2bf(o2), b3 = f2bf(o3);
        uint64_t packed = (uint64_t)b0 | ((uint64_t)b1 << 16) | ((uint64_t)b2 << 32) | ((uint64_t)b3 << 48);
        *(uint64_t*)(hbout + j) = packed;
        if (cell == 2) {
            __builtin_nontemporal_store(packed, (uint64_t*)(X_all + ((size_t)t * BSZ + b) * HID + j));
        }
    }
}

// ---------------- logsumexp + target gather -> LP[t][b] ----------------
__global__ void __launch_bounds__(256) k_lse2(const float* __restrict__ part, const int* __restrict__ target,
                       int c0, float* __restrict__ LP) {
    int wid = threadIdx.x >> 6, lane = threadIdx.x & 63;
    int r = blockIdx.x * 4 + wid;
    const float* row = part + (size_t)r * VOC;
    float v[8];
#pragma unroll
    for (int e = 0; e < 8; e++) v[e] = row[e * 64 + lane];
    float m = v[0];
#pragma unroll
    for (int e = 1; e < 8; e++) m = fmaxf(m, v[e]);
    for (int o = 32; o > 0; o >>= 1) m = fmaxf(m, __shfl_xor(m, o));
    float s = 0.f;
#pragma unroll
    for (int e = 0; e < 8; e++) s += __expf(v[e] - m);
    for (int o = 32; o > 0; o >>= 1) s += __shfl_xor(s, o);
    int t = c0 + (r >> 8), b = r & 255;
    int tg = target[b * TLEN + t];
    float tv = 0.f;
#pragma unroll
    for (int e = 0; e < 8; e++) if (e * 64 + lane == tg) tv = v[e];
    for (int o = 32; o > 0; o >>= 1) tv += __shfl_xor(tv, o);
    if (lane == 0) LP[(size_t)t * BSZ + b] = tv - (m + logf(s));
}

// ---------------- final: out[b] = sum_t LP[t][b] ----------------
__global__ void k_out(const float* __restrict__ LP, float* __restrict__ out) {
    int b = threadIdx.x;
    float s = 0.f;
    for (int t = 0; t < TLEN; t++) s += LP[(size_t)t * BSZ + b];
    out[b] = s;
}

// ---------------- host ----------------
extern "C" void kernel_launch(void* const* d_in, const int* in_sizes, int n_in,
                              void* d_out, int out_size, void* d_ws, size_t ws_size,
                              hipStream_t stream) {
    const int*   target = (const int*)  d_in[0];
    const float* emb    = (const float*)d_in[1];
    const float* projW  = (const float*)d_in[2];
    const float* projb  = (const float*)d_in[3];
    const float* gWih   = (const float*)d_in[4];
    const float* gWhh   = (const float*)d_in[5];
    const float* gbih   = (const float*)d_in[6];
    const float* gbhh   = (const float*)d_in[7];
    const float* ln_s   = (const float*)d_in[8];
    const float* ln_b   = (const float*)d_in[9];
    const float* fc1W   = (const float*)d_in[10];
    const float* fc1b   = (const float*)d_in[11];
    const float* fc2W   = (const float*)d_in[12];
    const float* fc2b   = (const float*)d_in[13];
    float* out = (float*)d_out;

    char* ws = (char*)d_ws;
    size_t off = 0;
    auto alloc = [&](size_t bytes) { void* p = ws + off; off += (bytes + 511) & ~511ull; return p; };
    u16* emb_bf   = (u16*)alloc((size_t)VOC * EMB * 2);
    u16* projW_bf = (u16*)alloc((size_t)HID * EMB * 2);
    u16* Wih_bf   = (u16*)alloc((size_t)3 * B3H * HID * 2);
    u16* Whh_bf   = (u16*)alloc((size_t)3 * B3H * HID * 2);
    u16* X_all    = (u16*)alloc((size_t)TLEN * BSZ * HID * 2);   // becomes H2_all as loop consumes it
    float* h_f32  = (float*)alloc((size_t)2 * 3 * BSZ * HID * 4); // [slot][cell][B][H]
    u16*   h_bf   = (u16*)alloc((size_t)2 * 3 * BSZ * HID * 2);
    float* LP     = (float*)alloc((size_t)TLEN * BSZ * 4);
    float* giP    = (float*)alloc(3 * SLAB * 4);                  // 9.4 MB (loop only)
    float* ghP    = (float*)alloc(3 * SLAB * 4);                  // 9.4 MB (loop only)
    if (off > ws_size) return;

    // tail overlays (loop partials dead after loop; h_f32 dead after loop)
    u16*   fc1W_bf = (u16*)giP;                                   // 4 MB
    u16*   fc2W_bf = (u16*)((char*)giP + (size_t)2048 * HID * 2); // 2 MB
    u16*   a1c     = (u16*)ghP;                                   // 8.4 MB (CH=8)
    float* partc   = (float*)h_f32;                               // 4.2 MB (CH=8)

    auto cvt = [&](const float* s, u16* d, int n) {
        k_convert<<<dim3((n / 4 + 255) / 256), 256, 0, stream>>>(s, d, n);
    };
    cvt(emb,   emb_bf,   VOC * EMB);
    cvt(projW, projW_bf, HID * EMB);
    cvt(gWih,  Wih_bf,   3 * B3H * HID);
    cvt(gWhh,  Whh_bf,   3 * B3H * HID);
    (void)hipMemsetAsync(h_f32, 0, (size_t)2 * 3 * BSZ * HID * 4, stream);
    (void)hipMemsetAsync(h_bf,  0, (size_t)2 * 3 * BSZ * HID * 2, stream);

    // X_all[t*B+b] = emb[tok] @ projW^T + projb  (staged, gathered A)
    k_proj_s<<<dim3(HID / 128, (TLEN * BSZ) / 128), 256, 0, stream>>>(emb_bf, projW_bf, projb, target, X_all);

    // wavefront over (cell, t): wave wv handles cell c at t = wv - c
    for (int wv = 0; wv < TLEN + 2; wv++) {
        k_gstep<<<dim3(576), 256, 0, stream>>>(wv, X_all, h_bf, Wih_bf, Whh_bf, giP, ghP);
        k_wew<<<dim3(BSZ / 4, 3), 256, 0, stream>>>(wv, giP, ghP, gbih, gbhh, h_f32, h_bf, X_all, ln_s, ln_b);
    }

    // tail: fc1 -> fc2 -> log-softmax over T in chunks of CH=8
    cvt(fc1W, fc1W_bf, 2048 * HID);
    cvt(fc2W, fc2W_bf, VOC * 2048);
    const int CH = 8;
    for (int c0 = 0; c0 < TLEN; c0 += CH) {
        int M = CH * BSZ;  // 2048 rows
        const u16* Ain = X_all + (size_t)c0 * BSZ * HID;   // H2 rows for steps [c0, c0+CH)
        k_gemm_s<HID, 1><<<dim3(2048 / 128, M / 128), 256, 0, stream>>>(Ain, fc1W_bf, fc1b, a1c, 2048);
        k_gemm_s<2048, 2><<<dim3(VOC / 128, M / 128), 256, 0, stream>>>(a1c, fc2W_bf, fc2b, partc, VOC);
        k_lse2<<<dim3(M / 4), 256, 0, stream>>>(partc, target, c0, LP);
    }
    k_out<<<1, 256, 0, stream>>>(LP, out);
}

// Round 9
// 4949.308 us; speedup vs baseline: 1.1240x; 1.1240x over previous
//
#include <hip/hip_runtime.h>
#include <stdint.h>

// ---------------- constants ----------------
#define HID   1024          // H
#define B3H   3072          // 3H
#define BSZ   256           // batch
#define TLEN  128           // seq len
#define VOC   512
#define EMB   512
#define SLAB  ((size_t)BSZ * B3H)    // one [256,3072] f32 slab (elements)

typedef unsigned short u16;
typedef short bf16x8 __attribute__((ext_vector_type(8)));
typedef float f32x4  __attribute__((ext_vector_type(4)));

__device__ __forceinline__ float bf2f(u16 u) {
    union { float f; uint32_t i; } c; c.i = ((uint32_t)u) << 16; return c.f;
}
__device__ __forceinline__ u16 f2bf(float f) {
    union { float f; uint32_t i; } c; c.f = f;
    uint32_t u = c.i;
    return (u16)((u + 0x7FFFu + ((u >> 16) & 1u)) >> 16);   // RNE
}
__device__ __forceinline__ float sigm(float x)  { return 1.f / (1.f + __expf(-x)); }
__device__ __forceinline__ float tanhf_(float x) {
    float e = __expf(-2.f * fabsf(x));
    float r = (1.f - e) / (1.f + e);
    return x < 0.f ? -r : r;
}

// async global->LDS, 16B per lane (wave-uniform LDS base + lane*16)
__device__ __forceinline__ void gll16(const u16* g, u16* l) {
    __builtin_amdgcn_global_load_lds(
        (__attribute__((address_space(1))) void*)(u16*)g,
        (__attribute__((address_space(3))) void*)l, 16, 0, 0);
}

// stage one 128x32 bf16 tile (row-major src, stride ld) into linear LDS [128][32]
__device__ __forceinline__ void stage_tile(const u16* __restrict__ src, int ld,
                                           u16* __restrict__ lds, int wid, int lane) {
#pragma unroll
    for (int i = 0; i < 2; i++) {
        int row16 = wid * 2 + i;                       // 0..7 (16-row groups)
        const u16* g = src + (size_t)(row16 * 16 + (lane >> 2)) * ld + (lane & 3) * 8;
        u16* l = lds + row16 * 16 * 32;                // wave-uniform base
        gll16(g, l);
    }
}
// stage one 64x32 tile: 1 instr per wave (wave w covers rows w*16..w*16+15)
__device__ __forceinline__ void stage_tile64(const u16* __restrict__ src, int ld,
                                             u16* __restrict__ lds, int wid, int lane) {
    const u16* g = src + (size_t)(wid * 16 + (lane >> 2)) * ld + (lane & 3) * 8;
    gll16(g, lds + wid * 16 * 32);
}

// 128x128 x KTOT staged GEMM core: 4 waves, each 64x64 (acc[4][4])
template<int KTOT>
__device__ __forceinline__ void gemm_tiles(const u16* __restrict__ A, const u16* __restrict__ W,
                                           f32x4 acc[4][4], int wid, int lane) {
    __shared__ u16 As[2][128 * 32], Ws[2][128 * 32];
    const int r = lane & 15, g8 = (lane >> 4) * 8;
    const int mq = wid & 1, nq = wid >> 1;
    int buf = 0;
    stage_tile(A, KTOT, As[0], wid, lane);
    stage_tile(W, KTOT, Ws[0], wid, lane);
    __syncthreads();
    for (int k0 = 0; k0 < KTOT; k0 += 32) {
        if (k0 + 32 < KTOT) {
            stage_tile(A + k0 + 32, KTOT, As[buf ^ 1], wid, lane);
            stage_tile(W + k0 + 32, KTOT, Ws[buf ^ 1], wid, lane);
        }
        bf16x8 a[4], b[4];
#pragma unroll
        for (int i = 0; i < 4; i++) a[i] = *(const bf16x8*)(As[buf] + (mq * 64 + i * 16 + r) * 32 + g8);
#pragma unroll
        for (int i = 0; i < 4; i++) b[i] = *(const bf16x8*)(Ws[buf] + (nq * 64 + i * 16 + r) * 32 + g8);
#pragma unroll
        for (int mi = 0; mi < 4; mi++)
#pragma unroll
            for (int ni = 0; ni < 4; ni++)
                acc[mi][ni] = __builtin_amdgcn_mfma_f32_16x16x32_bf16(a[mi], b[ni], acc[mi][ni], 0, 0, 0);
        __syncthreads();
        buf ^= 1;
    }
}

// 64(M) x 128(N) x KTOT staged core: 4 waves, each 32x64 (acc[2][4]); LDS 24 KB
template<int KTOT>
__device__ __forceinline__ void gemm_tiles64(const u16* __restrict__ A, const u16* __restrict__ W,
                                             f32x4 acc[2][4], int wid, int lane) {
    __shared__ u16 As[2][64 * 32], Ws[2][128 * 32];
    const int r = lane & 15, g8 = (lane >> 4) * 8;
    const int mq = wid & 1, nq = wid >> 1;
    int buf = 0;
    stage_tile64(A, KTOT, As[0], wid, lane);
    stage_tile(W, KTOT, Ws[0], wid, lane);
    __syncthreads();
    for (int k0 = 0; k0 < KTOT; k0 += 32) {
        if (k0 + 32 < KTOT) {
            stage_tile64(A + k0 + 32, KTOT, As[buf ^ 1], wid, lane);
            stage_tile(W + k0 + 32, KTOT, Ws[buf ^ 1], wid, lane);
        }
        bf16x8 a[2], b[4];
#pragma unroll
        for (int i = 0; i < 2; i++) a[i] = *(const bf16x8*)(As[buf] + (mq * 32 + i * 16 + r) * 32 + g8);
#pragma unroll
        for (int i = 0; i < 4; i++) b[i] = *(const bf16x8*)(Ws[buf] + (nq * 64 + i * 16 + r) * 32 + g8);
#pragma unroll
        for (int mi = 0; mi < 2; mi++)
#pragma unroll
            for (int ni = 0; ni < 4; ni++)
                acc[mi][ni] = __builtin_amdgcn_mfma_f32_16x16x32_bf16(a[mi], b[ni], acc[mi][ni], 0, 0, 0);
        __syncthreads();
        buf ^= 1;
    }
}

// ---------------- tiny utility kernels ----------------
__global__ void k_convert(const float* __restrict__ in, u16* __restrict__ out, int n) {
    int i = (blockIdx.x * 256 + threadIdx.x) * 4;
    if (i >= n) return;
    float4 f = *(const float4*)(in + i);
    uint32_t lo = (uint32_t)f2bf(f.x) | ((uint32_t)f2bf(f.y) << 16);
    uint32_t hi = (uint32_t)f2bf(f.z) | ((uint32_t)f2bf(f.w) << 16);
    uint2 p; p.x = lo; p.y = hi;
    *(uint2*)(out + i) = p;
}

// ---------------- staged proj: X_all = emb[tok] @ projW^T + projb (gathered A) ----------------
__global__ void __launch_bounds__(256) k_proj_s(const u16* __restrict__ emb_bf, const u16* __restrict__ projW_bf,
                        const float* __restrict__ projb, const int* __restrict__ target,
                        u16* __restrict__ X_all) {
    int nt = blockIdx.x, mt = blockIdx.y;
    int wid = threadIdx.x >> 6, lane = threadIdx.x & 63;
    __shared__ u16 As[2][128 * 32], Ws[2][128 * 32];
    const u16* arow[2];
#pragma unroll
    for (int i = 0; i < 2; i++) {
        int lr = (wid * 2 + i) * 16 + (lane >> 2);     // 0..127
        int gr = mt * 128 + lr;
        int t = gr >> 8, b = gr & 255;
        int tok = (t == 0) ? 0 : target[b * TLEN + t - 1];
        arow[i] = emb_bf + (size_t)tok * EMB + (lane & 3) * 8;
    }
    const u16* W = projW_bf + (size_t)(nt * 128) * EMB;
    const int r = lane & 15, g8 = (lane >> 4) * 8;
    const int mq = wid & 1, nq = wid >> 1;
    f32x4 acc[4][4] = {};
    int buf = 0;
#pragma unroll
    for (int i = 0; i < 2; i++) gll16(arow[i], As[0] + (wid * 2 + i) * 512);
    stage_tile(W, EMB, Ws[0], wid, lane);
    __syncthreads();
    for (int k0 = 0; k0 < EMB; k0 += 32) {
        if (k0 + 32 < EMB) {
#pragma unroll
            for (int i = 0; i < 2; i++) gll16(arow[i] + k0 + 32, As[buf ^ 1] + (wid * 2 + i) * 512);
            stage_tile(W + k0 + 32, EMB, Ws[buf ^ 1], wid, lane);
        }
        bf16x8 a[4], b[4];
#pragma unroll
        for (int i = 0; i < 4; i++) a[i] = *(const bf16x8*)(As[buf] + (mq * 64 + i * 16 + r) * 32 + g8);
#pragma unroll
        for (int i = 0; i < 4; i++) b[i] = *(const bf16x8*)(Ws[buf] + (nq * 64 + i * 16 + r) * 32 + g8);
#pragma unroll
        for (int mi = 0; mi < 4; mi++)
#pragma unroll
            for (int ni = 0; ni < 4; ni++)
                acc[mi][ni] = __builtin_amdgcn_mfma_f32_16x16x32_bf16(a[mi], b[ni], acc[mi][ni], 0, 0, 0);
        __syncthreads();
        buf ^= 1;
    }
    int c = lane & 15, r0 = (lane >> 4) * 4;
#pragma unroll
    for (int mi = 0; mi < 4; mi++)
#pragma unroll
        for (int e = 0; e < 4; e++) {
            size_t row = (size_t)(mt * 128 + mq * 64 + mi * 16 + r0 + e);
#pragma unroll
            for (int ni = 0; ni < 4; ni++) {
                int col = nt * 128 + nq * 64 + ni * 16 + c;
                X_all[row * HID + col] = f2bf(acc[mi][ni][e] + projb[col]);
            }
        }
}

// ============== wavefront GEMM (staged 128^2): 6 groups x 2 Mtiles x 24 Ntiles ==============
// bid = g*48 + mt*24 + nt  (W-panel pair mt=0/1 differ by 24 == 0 mod 8 -> same XCD)
__global__ void __launch_bounds__(256) k_gstep(int wv,
    const u16* __restrict__ X_all, const u16* __restrict__ h_bf,
    const u16* __restrict__ Wih, const u16* __restrict__ Whh,
    float* __restrict__ giP, float* __restrict__ ghP) {
    int bid = blockIdx.x;
    int g = bid / 48, rem = bid % 48, mt = rem / 24, nt = rem % 24;
    int cell = g % 3; bool isgh = (g >= 3);
    int t = wv - cell;
    if (t < 0 || t >= TLEN) return;
    int rd = (wv + 1) & 1;
    const u16* A;
    if (isgh)            A = h_bf + (size_t)(rd * 3 + cell)     * BSZ * HID;
    else if (cell == 0)  A = X_all + (size_t)t * BSZ * HID;
    else                 A = h_bf + (size_t)(rd * 3 + cell - 1) * BSZ * HID;
    A += (size_t)(mt * 128) * HID;
    const u16* W = (isgh ? Whh : Wih) + (size_t)cell * B3H * HID + (size_t)(nt * 128) * HID;
    float*     C = (isgh ? ghP : giP) + (size_t)cell * SLAB + (size_t)(mt * 128) * B3H + nt * 128;

    int wid = threadIdx.x >> 6, lane = threadIdx.x & 63;
    f32x4 acc[4][4] = {};
    gemm_tiles<HID>(A, W, acc, wid, lane);
    int mq = wid & 1, nq = wid >> 1;
    int c = lane & 15, r0 = (lane >> 4) * 4;
#pragma unroll
    for (int mi = 0; mi < 4; mi++)
#pragma unroll
        for (int e = 0; e < 4; e++) {
            float* Cw = C + (size_t)(mq * 64 + mi * 16 + r0 + e) * B3H;
#pragma unroll
            for (int ni = 0; ni < 4; ni++)
                __builtin_nontemporal_store(acc[mi][ni][e], Cw + nq * 64 + ni * 16 + c);
        }
}

// ============== generic staged GEMM for the tail (128-row tiles) ==============
// EPI: 1 = bias+relu -> bf16 ; 2 = bias -> f32
template<int KTOT, int EPI>
__global__ void __launch_bounds__(256) k_gemm_s(const u16* __restrict__ A, const u16* __restrict__ W,
                                                const float* __restrict__ bias, void* __restrict__ Cout, int ldc) {
    int nt = blockIdx.x, mt = blockIdx.y;
    int wid = threadIdx.x >> 6, lane = threadIdx.x & 63;
    f32x4 acc[4][4] = {};
    gemm_tiles<KTOT>(A + (size_t)(mt * 128) * KTOT, W + (size_t)(nt * 128) * KTOT, acc, wid, lane);
    int mq = wid & 1, nq = wid >> 1;
    int c = lane & 15, r0 = (lane >> 4) * 4;
#pragma unroll
    for (int mi = 0; mi < 4; mi++)
#pragma unroll
        for (int e = 0; e < 4; e++) {
            size_t row = (size_t)(mt * 128 + mq * 64 + mi * 16 + r0 + e);
#pragma unroll
            for (int ni = 0; ni < 4; ni++) {
                int col = nt * 128 + nq * 64 + ni * 16 + c;
                float x = acc[mi][ni][e] + bias[col];
                if (EPI == 1) ((u16*)Cout)[row * ldc + col] = f2bf(fmaxf(x, 0.f));
                else          ((float*)Cout)[row * ldc + col] = x;
            }
        }
}

// ============== tail GEMM, 64-row tiles (for fc2: more blocks, latency-bound shape) ==============
template<int KTOT>
__global__ void __launch_bounds__(256) k_gemm_s64(const u16* __restrict__ A, const u16* __restrict__ W,
                                                  const float* __restrict__ bias, float* __restrict__ Cout, int ldc) {
    int nt = blockIdx.x, mt = blockIdx.y;
    int wid = threadIdx.x >> 6, lane = threadIdx.x & 63;
    f32x4 acc[2][4] = {};
    gemm_tiles64<KTOT>(A + (size_t)(mt * 64) * KTOT, W + (size_t)(nt * 128) * KTOT, acc, wid, lane);
    int mq = wid & 1, nq = wid >> 1;
    int c = lane & 15, r0 = (lane >> 4) * 4;
#pragma unroll
    for (int mi = 0; mi < 2; mi++)
#pragma unroll
        for (int e = 0; e < 4; e++) {
            size_t row = (size_t)(mt * 64 + mq * 32 + mi * 16 + r0 + e);
#pragma unroll
            for (int ni = 0; ni < 4; ni++) {
                int col = nt * 128 + nq * 64 + ni * 16 + c;
                Cout[row * ldc + col] = acc[mi][ni][e] + bias[col];
            }
        }
}

// ============== wavefront ew: 3 cells, 1 wave per batch row ==============
__global__ void __launch_bounds__(256) k_wew(int wv,
    const float* __restrict__ giP, const float* __restrict__ ghP,
    const float* __restrict__ bih_all, const float* __restrict__ bhh_all,
    float* __restrict__ h_f32, u16* __restrict__ h_bf, u16* __restrict__ X_all,
    const float* __restrict__ ln_s_all, const float* __restrict__ ln_b_all) {
    int cell = blockIdx.y;
    int t = wv - cell;
    if (t < 0 || t >= TLEN) return;
    int wid = threadIdx.x >> 6, lane = threadIdx.x & 63;
    int b = blockIdx.x * 4 + wid;
    int rd = (wv + 1) & 1, wr = wv & 1;

    const float* gi  = giP + (size_t)cell * SLAB + (size_t)b * B3H;
    const float* gh  = ghP + (size_t)cell * SLAB + (size_t)b * B3H;
    const float* bih = bih_all + cell * B3H;
    const float* bhh = bhh_all + cell * B3H;
    const float* lns = ln_s_all + cell * HID;
    const float* lnb = ln_b_all + cell * HID;
    const float* hprev = h_f32 + ((size_t)(rd * 3 + cell) * BSZ + b) * HID;
    float*       hout  = h_f32 + ((size_t)(wr * 3 + cell) * BSZ + b) * HID;
    u16*         hbout = h_bf  + ((size_t)(wr * 3 + cell) * BSZ + b) * HID;
    const float* xsrcf = (cell > 0) ? h_f32 + ((size_t)(rd * 3 + cell - 1) * BSZ + b) * HID : nullptr;
    const u16*   xsrcb = X_all + ((size_t)t * BSZ + b) * HID;

    float val[16], s = 0.f, s2 = 0.f;
#pragma unroll
    for (int e = 0; e < 4; e++) {
        int j = e * 256 + lane * 4;
        float gg[3][4], hh[3][4];
#pragma unroll
        for (int g = 0; g < 3; g++) {
            int o = g * HID + j;
            f32x4 a = __builtin_nontemporal_load((const f32x4*)(gi + o));
            float4 ab = *(const float4*)(bih + o);
            gg[g][0] = a[0] + ab.x; gg[g][1] = a[1] + ab.y; gg[g][2] = a[2] + ab.z; gg[g][3] = a[3] + ab.w;
            f32x4 h4 = __builtin_nontemporal_load((const f32x4*)(gh + o));
            float4 hb = *(const float4*)(bhh + o);
            hh[g][0] = h4[0] + hb.x; hh[g][1] = h4[1] + hb.y; hh[g][2] = h4[2] + hb.z; hh[g][3] = h4[3] + hb.w;
        }
        float4 hp = *(const float4*)(hprev + j);
        float hpv[4] = {hp.x, hp.y, hp.z, hp.w};
        float xv[4];
        if (cell == 0) {
            ushort4 u = *(const ushort4*)(xsrcb + j);
            xv[0] = bf2f(u.x); xv[1] = bf2f(u.y); xv[2] = bf2f(u.z); xv[3] = bf2f(u.w);
        } else {
            float4 x4 = *(const float4*)(xsrcf + j);
            xv[0] = x4.x; xv[1] = x4.y; xv[2] = x4.z; xv[3] = x4.w;
        }
#pragma unroll
        for (int q = 0; q < 4; q++) {
            float r = sigm(gg[0][q] + hh[0][q]);
            float z = sigm(gg[1][q] + hh[1][q]);
            float n = tanhf_(gg[2][q] + r * hh[2][q]);
            float v = (1.f - z) * n + z * hpv[q] + xv[q];
            val[e * 4 + q] = v; s += v; s2 += v * v;
        }
    }
#pragma unroll
    for (int o = 32; o > 0; o >>= 1) { s += __shfl_xor(s, o); s2 += __shfl_xor(s2, o); }
    float mu = s * (1.f / HID);
    float inv = rsqrtf(s2 * (1.f / HID) - mu * mu + 1e-5f);
#pragma unroll
    for (int e = 0; e < 4; e++) {
        int j = e * 256 + lane * 4;
        float4 sc = *(const float4*)(lns + j);
        float4 bi = *(const float4*)(lnb + j);
        float o0 = (val[e * 4 + 0] - mu) * inv * sc.x + bi.x;
        float o1 = (val[e * 4 + 1] - mu) * inv * sc.y + bi.y;
        float o2 = (val[e * 4 + 2] - mu) * inv * sc.z + bi.z;
        float o3 = (val[e * 4 + 3] - mu) * inv * sc.w + bi.w;
        float4 of; of.x = o0; of.y = o1; of.z = o2; of.w = o3;
        *(float4*)(hout + j) = of;
        u16 b0 = f2bf(o0), b1 = f2bf(o1), b2 = f2bf(o2), b3 = f2bf(o3);
        uint64_t packed = (uint64_t)b0 | ((uint64_t)b1 << 16) | ((uint64_t)b2 << 32) | ((uint64_t)b3 << 48);
        *(uint64_t*)(hbout + j) = packed;
        if (cell == 2) {
            __builtin_nontemporal_store(packed, (uint64_t*)(X_all + ((size_t)t * BSZ + b) * HID + j));
        }
    }
}

// ---------------- logsumexp + target gather -> LP[t][b] ----------------
__global__ void __launch_bounds__(256) k_lse2(const float* __restrict__ part, const int* __restrict__ target,
                       int c0, float* __restrict__ LP) {
    int wid = threadIdx.x >> 6, lane = threadIdx.x & 63;
    int r = blockIdx.x * 4 + wid;
    const float* row = part + (size_t)r * VOC;
    float v[8];
#pragma unroll
    for (int e = 0; e < 8; e++) v[e] = row[e * 64 + lane];
    float m = v[0];
#pragma unroll
    for (int e = 1; e < 8; e++) m = fmaxf(m, v[e]);
    for (int o = 32; o > 0; o >>= 1) m = fmaxf(m, __shfl_xor(m, o));
    float s = 0.f;
#pragma unroll
    for (int e = 0; e < 8; e++) s += __expf(v[e] - m);
    for (int o = 32; o > 0; o >>= 1) s += __shfl_xor(s, o);
    int t = c0 + (r >> 8), b = r & 255;
    int tg = target[b * TLEN + t];
    float tv = 0.f;
#pragma unroll
    for (int e = 0; e < 8; e++) if (e * 64 + lane == tg) tv = v[e];
    for (int o = 32; o > 0; o >>= 1) tv += __shfl_xor(tv, o);
    if (lane == 0) LP[(size_t)t * BSZ + b] = tv - (m + logf(s));
}

// ---------------- final: out[b] = sum_t LP[t][b] ----------------
__global__ void k_out(const float* __restrict__ LP, float* __restrict__ out) {
    int b = threadIdx.x;
    float s = 0.f;
    for (int t = 0; t < TLEN; t++) s += LP[(size_t)t * BSZ + b];
    out[b] = s;
}

// ---------------- host ----------------
extern "C" void kernel_launch(void* const* d_in, const int* in_sizes, int n_in,
                              void* d_out, int out_size, void* d_ws, size_t ws_size,
                              hipStream_t stream) {
    const int*   target = (const int*)  d_in[0];
    const float* emb    = (const float*)d_in[1];
    const float* projW  = (const float*)d_in[2];
    const float* projb  = (const float*)d_in[3];
    const float* gWih   = (const float*)d_in[4];
    const float* gWhh   = (const float*)d_in[5];
    const float* gbih   = (const float*)d_in[6];
    const float* gbhh   = (const float*)d_in[7];
    const float* ln_s   = (const float*)d_in[8];
    const float* ln_b   = (const float*)d_in[9];
    const float* fc1W   = (const float*)d_in[10];
    const float* fc1b   = (const float*)d_in[11];
    const float* fc2W   = (const float*)d_in[12];
    const float* fc2b   = (const float*)d_in[13];
    float* out = (float*)d_out;

    char* ws = (char*)d_ws;
    size_t off = 0;
    auto alloc = [&](size_t bytes) { void* p = ws + off; off += (bytes + 511) & ~511ull; return p; };
    u16* emb_bf   = (u16*)alloc((size_t)VOC * EMB * 2);
    u16* projW_bf = (u16*)alloc((size_t)HID * EMB * 2);
    u16* Wih_bf   = (u16*)alloc((size_t)3 * B3H * HID * 2);
    u16* Whh_bf   = (u16*)alloc((size_t)3 * B3H * HID * 2);
    u16* X_all    = (u16*)alloc((size_t)TLEN * BSZ * HID * 2);   // becomes H2_all as loop consumes it
    float* h_f32  = (float*)alloc((size_t)2 * 3 * BSZ * HID * 4); // [slot][cell][B][H]
    u16*   h_bf   = (u16*)alloc((size_t)2 * 3 * BSZ * HID * 2);
    float* LP     = (float*)alloc((size_t)TLEN * BSZ * 4);
    float* giP    = (float*)alloc(3 * SLAB * 4);                  // 9.4 MB (loop only)
    float* ghP    = (float*)alloc(3 * SLAB * 4);                  // 9.4 MB (loop only)
    if (off > ws_size) return;

    // tail overlays (loop partials dead after loop; h_f32 dead after loop)
    u16*   fc1W_bf = (u16*)giP;                                   // 4 MB
    u16*   fc2W_bf = (u16*)((char*)giP + (size_t)2048 * HID * 2); // 2 MB
    u16*   a1c     = (u16*)ghP;                                   // 8.4 MB (CH=8)
    float* partc   = (float*)h_f32;                               // 4.2 MB (CH=8)

    auto cvt = [&](const float* s, u16* d, int n) {
        k_convert<<<dim3((n / 4 + 255) / 256), 256, 0, stream>>>(s, d, n);
    };
    cvt(emb,   emb_bf,   VOC * EMB);
    cvt(projW, projW_bf, HID * EMB);
    cvt(gWih,  Wih_bf,   3 * B3H * HID);
    cvt(gWhh,  Whh_bf,   3 * B3H * HID);
    (void)hipMemsetAsync(h_f32, 0, (size_t)2 * 3 * BSZ * HID * 4, stream);
    (void)hipMemsetAsync(h_bf,  0, (size_t)2 * 3 * BSZ * HID * 2, stream);

    // X_all[t*B+b] = emb[tok] @ projW^T + projb  (staged, gathered A)
    k_proj_s<<<dim3(HID / 128, (TLEN * BSZ) / 128), 256, 0, stream>>>(emb_bf, projW_bf, projb, target, X_all);

    // wavefront over (cell, t): wave wv handles cell c at t = wv - c
    for (int wv = 0; wv < TLEN + 2; wv++) {
        k_gstep<<<dim3(288), 256, 0, stream>>>(wv, X_all, h_bf, Wih_bf, Whh_bf, giP, ghP);
        k_wew<<<dim3(BSZ / 4, 3), 256, 0, stream>>>(wv, giP, ghP, gbih, gbhh, h_f32, h_bf, X_all, ln_s, ln_b);
    }

    // tail: fc1 -> fc2 -> log-softmax over T in chunks of CH=8
    cvt(fc1W, fc1W_bf, 2048 * HID);
    cvt(fc2W, fc2W_bf, VOC * 2048);
    const int CH = 8;
    for (int c0 = 0; c0 < TLEN; c0 += CH) {
        int M = CH * BSZ;  // 2048 rows
        const u16* Ain = X_all + (size_t)c0 * BSZ * HID;   // H2 rows for steps [c0, c0+CH)
        k_gemm_s<HID, 1><<<dim3(2048 / 128, M / 128), 256, 0, stream>>>(Ain, fc1W_bf, fc1b, a1c, 2048);
        k_gemm_s64<2048><<<dim3(VOC / 128, M / 64), 256, 0, stream>>>(a1c, fc2W_bf, fc2b, partc, VOC);
        k_lse2<<<dim3(M / 4), 256, 0, stream>>>(partc, target, c0, LP);
    }
    k_out<<<1, 256, 0, stream>>>(LP, out);
}